// Round 1
// baseline (302.247 us; speedup 1.0000x reference)
//
#include <hip/hip_runtime.h>
#include <hip/hip_bf16.h>

#define H 1024
#define T 2048
#define B 32

typedef __attribute__((ext_vector_type(8))) __bf16 bf16x8;
typedef __attribute__((ext_vector_type(16))) float f32x16;
typedef __attribute__((ext_vector_type(4))) unsigned short u16x4;
typedef __attribute__((ext_vector_type(8))) unsigned short u16x8;

__device__ __forceinline__ unsigned short f2bf(float f) {
    unsigned int x = __float_as_uint(f);
    x += 0x7fffu + ((x >> 16) & 1u);
    return (unsigned short)(x >> 16);
}

// Pack W2 = W[:, H:2H] into bf16, layout Wp[(k>>3)][n][k&7]  (16B per (kg,n))
// so a B-fragment load for mfma_f32_32x32x16_bf16 is one coalesced 16B/lane load.
__global__ __launch_bounds__(256) void prep_w_kernel(const float* __restrict__ W,
                                                     unsigned short* __restrict__ Wp) {
    int gid = blockIdx.x * 256 + threadIdx.x;   // 131072 total
    int n = gid & (H - 1);
    int kg = gid >> 10;                          // 0..127
    const float* srcp = W + (size_t)n * (2 * H) + H + kg * 8;
    float4 f0 = *(const float4*)(srcp);
    float4 f1 = *(const float4*)(srcp + 4);
    u16x8 o;
    o[0] = f2bf(f0.x); o[1] = f2bf(f0.y); o[2] = f2bf(f0.z); o[3] = f2bf(f0.w);
    o[4] = f2bf(f1.x); o[5] = f2bf(f1.y); o[6] = f2bf(f1.z); o[7] = f2bf(f1.w);
    *(u16x8*)(Wp + (size_t)gid * 8) = o;
}

// hp[b][h] = sum_d hidden[b][d] * W[h][d] + bias[h]   (fp32, exact part)
__global__ __launch_bounds__(128) void prep_hp_kernel(const float* __restrict__ hidden,
                                                      const float* __restrict__ W,
                                                      const float* __restrict__ bias,
                                                      float* __restrict__ hp) {
    int b = blockIdx.y;
    int h = blockIdx.x * 128 + threadIdx.x;
    const float* hid = hidden + (size_t)b * H;
    const float* wr = W + (size_t)h * (2 * H);
    float acc = 0.f;
    for (int d = 0; d < H; d += 4) {
        float4 wv = *(const float4*)(wr + d);
        float4 hv = *(const float4*)(hid + d);
        acc += wv.x * hv.x + wv.y * hv.y + wv.z * hv.z + wv.w * hv.w;
    }
    hp[(size_t)b * H + h] = acc + bias[h];
}

// Main fused kernel: per block (b, 64-row t tile):
//  stage enc tile fp32->bf16 in LDS (swizzled), 8 waves each own 128 h-cols,
//  K-loop 32x32x16 bf16 MFMA, fused tanh + v-dot -> per-row scores.
__global__ __launch_bounds__(512) void energy_kernel(const float* __restrict__ enc,
                                                     const float* __restrict__ hp,
                                                     const float* __restrict__ vvec,
                                                     const unsigned short* __restrict__ Wp,
                                                     float* __restrict__ scores) {
    __shared__ __align__(16) unsigned short Atile[64 * H];   // 128 KB bf16
    __shared__ float scpart[8][64];

    const int tid = threadIdx.x;
    const int b = blockIdx.y;
    const int t0 = blockIdx.x * 64;

    // ---- stage enc[b][t0:t0+64][:] fp32 -> bf16 LDS, XOR-swizzled ----
    const float* src = enc + ((size_t)b * T + t0) * H;
    char* Ab = (char*)Atile;
    for (int it = 0; it < 32; ++it) {
        int r = it * 2 + (tid >> 8);           // 2 rows per iter, 512 threads
        int c4 = (tid & 255) * 4;              // 4 floats per thread
        float4 f = *(const float4*)(src + (size_t)r * H + c4);
        u16x4 p;
        p[0] = f2bf(f.x); p[1] = f2bf(f.y); p[2] = f2bf(f.z); p[3] = f2bf(f.w);
        int addr = r * 2048 + ((c4 * 2) ^ ((r & 7) << 4));
        *(u16x4*)(Ab + addr) = p;
    }
    __syncthreads();

    const int wave = tid >> 6;
    const int lane = tid & 63;
    const int l31 = lane & 31;
    const int hi = lane >> 5;
    const int swz = (l31 & 7) << 4;
    const char* Arow0 = Ab + l31 * 2048;
    const char* Arow1 = Ab + (32 + l31) * 2048;

    float pscore[32];
#pragma unroll
    for (int r = 0; r < 32; ++r) pscore[r] = 0.f;

    const size_t bH = (size_t)b * H;

    for (int nc = 0; nc < 2; ++nc) {
        const int n0 = wave * 128 + nc * 64;   // this wave's 64-col chunk
        f32x16 acc00, acc01, acc10, acc11;
#pragma unroll
        for (int i = 0; i < 16; ++i) { acc00[i] = 0.f; acc01[i] = 0.f; acc10[i] = 0.f; acc11[i] = 0.f; }
        const unsigned short* wp0 = Wp + ((size_t)hi * (H * 8)) + (size_t)(n0 + l31) * 8;
#pragma unroll 4
        for (int k0 = 0; k0 < H; k0 += 16) {
            int koff = (((k0 << 1) + (hi << 4)) ^ swz);
            bf16x8 a0 = *(const bf16x8*)(Arow0 + koff);
            bf16x8 a1 = *(const bf16x8*)(Arow1 + koff);
            const unsigned short* wpk = wp0 + ((size_t)(k0 >> 3) * (H * 8));
            bf16x8 b0 = *(const bf16x8*)(wpk);
            bf16x8 b1 = *(const bf16x8*)(wpk + 256);
            acc00 = __builtin_amdgcn_mfma_f32_32x32x16_bf16(a0, b0, acc00, 0, 0, 0);
            acc01 = __builtin_amdgcn_mfma_f32_32x32x16_bf16(a0, b1, acc01, 0, 0, 0);
            acc10 = __builtin_amdgcn_mfma_f32_32x32x16_bf16(a1, b0, acc10, 0, 0, 0);
            acc11 = __builtin_amdgcn_mfma_f32_32x32x16_bf16(a1, b1, acc11, 0, 0, 0);
        }
        // fused epilogue: energy = tanh(acc + hp[col]); pscore += v[col]*energy
        const int col0 = n0 + l31, col1 = n0 + 32 + l31;
        const float hp0 = hp[bH + col0], hp1 = hp[bH + col1];
        const float v0 = vvec[col0], v1 = vvec[col1];
#pragma unroll
        for (int r = 0; r < 16; ++r) {
            pscore[r]      += v0 * tanhf(acc00[r] + hp0) + v1 * tanhf(acc01[r] + hp1);
            pscore[16 + r] += v0 * tanhf(acc10[r] + hp0) + v1 * tanhf(acc11[r] + hp1);
        }
    }

    // reduce each row-partial across the 32 lanes (cols) of this half-wave
#pragma unroll
    for (int r = 0; r < 32; ++r) {
        float s = pscore[r];
        s += __shfl_xor(s, 1);
        s += __shfl_xor(s, 2);
        s += __shfl_xor(s, 4);
        s += __shfl_xor(s, 8);
        s += __shfl_xor(s, 16);
        pscore[r] = s;
    }
    if (l31 == 0) {
        // C/D layout: row = (reg&3) + 8*(reg>>2) + 4*hi
#pragma unroll
        for (int r = 0; r < 16; ++r) {
            int m0 = (r & 3) + 8 * (r >> 2) + 4 * hi;
            scpart[wave][m0] = pscore[r];
            scpart[wave][32 + m0] = pscore[16 + r];
        }
    }
    __syncthreads();
    if (tid < 64) {
        float s = 0.f;
#pragma unroll
        for (int w = 0; w < 8; ++w) s += scpart[w][tid];
        scores[(size_t)b * T + t0 + tid] = s;
    }
}

__global__ __launch_bounds__(256) void softmax_kernel(const float* __restrict__ sc,
                                                      float* __restrict__ out) {
    int b = blockIdx.x;
    int tid = threadIdx.x;
    int wave = tid >> 6, lane = tid & 63;
    const float* row = sc + (size_t)b * T;
    float vals[8];
    float m = -1e30f;
#pragma unroll
    for (int i = 0; i < 8; ++i) { vals[i] = row[tid + 256 * i]; m = fmaxf(m, vals[i]); }
#pragma unroll
    for (int s = 1; s < 64; s <<= 1) m = fmaxf(m, __shfl_xor(m, s));
    __shared__ float red[4];
    __shared__ float red2[4];
    if (lane == 0) red[wave] = m;
    __syncthreads();
    m = fmaxf(fmaxf(red[0], red[1]), fmaxf(red[2], red[3]));
    float sum = 0.f;
#pragma unroll
    for (int i = 0; i < 8; ++i) { vals[i] = expf(vals[i] - m); sum += vals[i]; }
#pragma unroll
    for (int s = 1; s < 64; s <<= 1) sum += __shfl_xor(sum, s);
    if (lane == 0) red2[wave] = sum;
    __syncthreads();
    sum = red2[0] + red2[1] + red2[2] + red2[3];
    float inv = 1.0f / sum;
#pragma unroll
    for (int i = 0; i < 8; ++i) out[(size_t)b * T + tid + 256 * i] = vals[i] * inv;
}

extern "C" void kernel_launch(void* const* d_in, const int* in_sizes, int n_in,
                              void* d_out, int out_size, void* d_ws, size_t ws_size,
                              hipStream_t stream) {
    (void)in_sizes; (void)n_in; (void)out_size; (void)ws_size;
    const float* hidden = (const float*)d_in[0];   // [1,B,H]
    const float* enc    = (const float*)d_in[1];   // [B,T,H]
    const float* W      = (const float*)d_in[2];   // [H,2H]
    const float* bias   = (const float*)d_in[3];   // [H]
    const float* v      = (const float*)d_in[4];   // [H]
    float* out = (float*)d_out;                    // [B,1,T]

    unsigned short* Wp = (unsigned short*)d_ws;                              // 2 MB
    float* hp = (float*)((char*)d_ws + 2 * 1024 * 1024);                     // 128 KB
    float* sc = (float*)((char*)d_ws + 2 * 1024 * 1024 + 128 * 1024);        // 256 KB

    prep_w_kernel<<<dim3(512), dim3(256), 0, stream>>>(W, Wp);
    prep_hp_kernel<<<dim3(8, B), dim3(128), 0, stream>>>(hidden, W, bias, hp);
    energy_kernel<<<dim3(T / 64, B), dim3(512), 0, stream>>>(enc, hp, v, Wp, sc);
    softmax_kernel<<<dim3(B), dim3(256), 0, stream>>>(sc, out);
}

// Round 2
// 246.638 us; speedup vs baseline: 1.2255x; 1.2255x over previous
//
#include <hip/hip_runtime.h>
#include <hip/hip_bf16.h>

#define H 1024
#define T 2048
#define B 32
#define BK 128
#define NCHUNK 8

typedef __attribute__((ext_vector_type(8))) __bf16 bf16x8;
typedef __attribute__((ext_vector_type(16))) float f32x16;
typedef __attribute__((ext_vector_type(8))) unsigned short u16x8;

__device__ __forceinline__ unsigned short f2bf(float f) {
    unsigned int x = __float_as_uint(f);
    x += 0x7fffu + ((x >> 16) & 1u);
    return (unsigned short)(x >> 16);
}

__device__ __forceinline__ float fast_tanh(float x) {
    // tanh(x) = 1 - 2/(e^{2x}+1); exact at +/-inf, NaN-free for finite x
    float t = __expf(2.0f * x);
    return 1.0f - 2.0f * __builtin_amdgcn_rcpf(t + 1.0f);
}

// Pack W2 = W[:, H:2H] into bf16, layout Wp[kg][n][8] (kg = k>>3), 16B per (kg,n)
__global__ __launch_bounds__(256) void prep_w_kernel(const float* __restrict__ W,
                                                     unsigned short* __restrict__ Wp) {
    int gid = blockIdx.x * 256 + threadIdx.x;   // 131072 total
    int n = gid & (H - 1);
    int kg = gid >> 10;                          // 0..127
    const float* srcp = W + (size_t)n * (2 * H) + H + kg * 8;
    float4 f0 = *(const float4*)(srcp);
    float4 f1 = *(const float4*)(srcp + 4);
    u16x8 o;
    o[0] = f2bf(f0.x); o[1] = f2bf(f0.y); o[2] = f2bf(f0.z); o[3] = f2bf(f0.w);
    o[4] = f2bf(f1.x); o[5] = f2bf(f1.y); o[6] = f2bf(f1.z); o[7] = f2bf(f1.w);
    *(u16x8*)(Wp + (size_t)gid * 8) = o;
}

// hp[b][h] = sum_d hidden[b][d] * W[h][d] + bias[h]   (fp32, exact part)
__global__ __launch_bounds__(128) void prep_hp_kernel(const float* __restrict__ hidden,
                                                      const float* __restrict__ W,
                                                      const float* __restrict__ bias,
                                                      float* __restrict__ hp) {
    int b = blockIdx.y;
    int h = blockIdx.x * 128 + threadIdx.x;
    const float* hid = hidden + (size_t)b * H;
    const float* wr = W + (size_t)h * (2 * H);
    float acc = 0.f;
    for (int d = 0; d < H; d += 4) {
        float4 wv = *(const float4*)(wr + d);
        float4 hv = *(const float4*)(hid + d);
        acc += wv.x * hv.x + wv.y * hv.y + wv.z * hv.z + wv.w * hv.w;
    }
    hp[(size_t)b * H + h] = acc + bias[h];
}

// Fused energy+score kernel, K-chunked double-buffered pipeline.
// Block = (b, 64-row t-tile), 8 waves; wave w owns output cols [128w,128w+128).
// LDS A-chunk layout (k-major): 16B unit at [ki][hi][row] -> byte ki*2048+hi*1024+row*16.
__global__ __launch_bounds__(512, 2) void energy_kernel(const float* __restrict__ enc,
                                                        const float* __restrict__ hp,
                                                        const float* __restrict__ vvec,
                                                        const unsigned short* __restrict__ Wp,
                                                        float* __restrict__ scores) {
    __shared__ __align__(16) unsigned short Abuf[2][NCHUNK * 1024];  // 2 x 16 KB
    __shared__ float scpart[8][64];

    const int tid = threadIdx.x;
    const int b = blockIdx.y;
    const int t0 = blockIdx.x * 64;
    const int wave = tid >> 6;
    const int lane = tid & 63;
    const int l31 = lane & 31;
    const int hi = lane >> 5;

    // staging assignment: thread = (ki = wave, row = lane), 16 consecutive k
    const float* st_src = enc + ((size_t)b * T + t0 + lane) * H + wave * 16;
    char* st_dst = (char*)&Abuf[0][0] + wave * 2048 + lane * 16;

    const char* Abase = (const char*)&Abuf[0][0];
    const int a_off = hi * 1024 + l31 * 16;

    // B cols for this wave: n = wave*128 + cg*32 + l31; kg = j*16 + ki*2 + hi
    const unsigned short* wp_col = Wp + (size_t)(wave * 128 + l31) * 8 + (size_t)hi * (H * 8);

    f32x16 acc[2][4];
#pragma unroll
    for (int rg = 0; rg < 2; ++rg)
#pragma unroll
        for (int cg = 0; cg < 4; ++cg)
#pragma unroll
            for (int i = 0; i < 16; ++i) acc[rg][cg][i] = 0.f;

    // ---- prologue: stage chunk 0 ----
    {
        float4 f0 = *(const float4*)(st_src + 0);
        float4 f1 = *(const float4*)(st_src + 4);
        float4 f2 = *(const float4*)(st_src + 8);
        float4 f3 = *(const float4*)(st_src + 12);
        u16x8 o0, o1;
        o0[0] = f2bf(f0.x); o0[1] = f2bf(f0.y); o0[2] = f2bf(f0.z); o0[3] = f2bf(f0.w);
        o0[4] = f2bf(f1.x); o0[5] = f2bf(f1.y); o0[6] = f2bf(f1.z); o0[7] = f2bf(f1.w);
        o1[0] = f2bf(f2.x); o1[1] = f2bf(f2.y); o1[2] = f2bf(f2.z); o1[3] = f2bf(f2.w);
        o1[4] = f2bf(f3.x); o1[5] = f2bf(f3.y); o1[6] = f2bf(f3.z); o1[7] = f2bf(f3.w);
        *(u16x8*)(st_dst) = o0;
        *(u16x8*)(st_dst + 1024) = o1;
    }
    __syncthreads();

    for (int j = 0; j < NCHUNK; ++j) {
        float4 f0, f1, f2, f3;
        const bool pf = (j < NCHUNK - 1);
        if (pf) {
            const float* p = st_src + (j + 1) * BK;
            f0 = *(const float4*)(p + 0);
            f1 = *(const float4*)(p + 4);
            f2 = *(const float4*)(p + 8);
            f3 = *(const float4*)(p + 12);
        }
        const char* Ab = Abase + (j & 1) * 16384;
        const unsigned short* wpj = wp_col + (size_t)(j * 16) * (H * 8);
#pragma unroll
        for (int ki = 0; ki < 8; ++ki) {
            bf16x8 a0 = *(const bf16x8*)(Ab + ki * 2048 + a_off);
            bf16x8 a1 = *(const bf16x8*)(Ab + ki * 2048 + a_off + 512);
            const unsigned short* wpk = wpj + (size_t)(ki * 2) * (H * 8);
            bf16x8 b0 = *(const bf16x8*)(wpk + 0 * 256);
            bf16x8 b1 = *(const bf16x8*)(wpk + 1 * 256);
            bf16x8 b2 = *(const bf16x8*)(wpk + 2 * 256);
            bf16x8 b3 = *(const bf16x8*)(wpk + 3 * 256);
            acc[0][0] = __builtin_amdgcn_mfma_f32_32x32x16_bf16(a0, b0, acc[0][0], 0, 0, 0);
            acc[0][1] = __builtin_amdgcn_mfma_f32_32x32x16_bf16(a0, b1, acc[0][1], 0, 0, 0);
            acc[0][2] = __builtin_amdgcn_mfma_f32_32x32x16_bf16(a0, b2, acc[0][2], 0, 0, 0);
            acc[0][3] = __builtin_amdgcn_mfma_f32_32x32x16_bf16(a0, b3, acc[0][3], 0, 0, 0);
            acc[1][0] = __builtin_amdgcn_mfma_f32_32x32x16_bf16(a1, b0, acc[1][0], 0, 0, 0);
            acc[1][1] = __builtin_amdgcn_mfma_f32_32x32x16_bf16(a1, b1, acc[1][1], 0, 0, 0);
            acc[1][2] = __builtin_amdgcn_mfma_f32_32x32x16_bf16(a1, b2, acc[1][2], 0, 0, 0);
            acc[1][3] = __builtin_amdgcn_mfma_f32_32x32x16_bf16(a1, b3, acc[1][3], 0, 0, 0);
        }
        if (pf) {
            u16x8 o0, o1;
            o0[0] = f2bf(f0.x); o0[1] = f2bf(f0.y); o0[2] = f2bf(f0.z); o0[3] = f2bf(f0.w);
            o0[4] = f2bf(f1.x); o0[5] = f2bf(f1.y); o0[6] = f2bf(f1.z); o0[7] = f2bf(f1.w);
            o1[0] = f2bf(f2.x); o1[1] = f2bf(f2.y); o1[2] = f2bf(f2.z); o1[3] = f2bf(f2.w);
            o1[4] = f2bf(f3.x); o1[5] = f2bf(f3.y); o1[6] = f2bf(f3.z); o1[7] = f2bf(f3.w);
            char* dst = st_dst + ((j + 1) & 1) * 16384;
            *(u16x8*)dst = o0;
            *(u16x8*)(dst + 1024) = o1;
        }
        __syncthreads();
    }

    // ---- fused epilogue: tanh + v-dot, once per block ----
    float pscore[2][16];
#pragma unroll
    for (int rg = 0; rg < 2; ++rg)
#pragma unroll
        for (int r = 0; r < 16; ++r) pscore[rg][r] = 0.f;

    const size_t bH = (size_t)b * H;
#pragma unroll
    for (int cg = 0; cg < 4; ++cg) {
        const int col = wave * 128 + cg * 32 + l31;
        const float hpv = hp[bH + col];
        const float vv = vvec[col];
#pragma unroll
        for (int rg = 0; rg < 2; ++rg)
#pragma unroll
            for (int r = 0; r < 16; ++r)
                pscore[rg][r] += vv * fast_tanh(acc[rg][cg][r] + hpv);
    }

#pragma unroll
    for (int rg = 0; rg < 2; ++rg)
#pragma unroll
        for (int r = 0; r < 16; ++r) {
            float s = pscore[rg][r];
            s += __shfl_xor(s, 1);
            s += __shfl_xor(s, 2);
            s += __shfl_xor(s, 4);
            s += __shfl_xor(s, 8);
            s += __shfl_xor(s, 16);
            pscore[rg][r] = s;
        }
    if (l31 == 0) {
#pragma unroll
        for (int rg = 0; rg < 2; ++rg)
#pragma unroll
            for (int r = 0; r < 16; ++r) {
                int m = (r & 3) + 8 * (r >> 2) + 4 * hi + rg * 32;
                scpart[wave][m] = pscore[rg][r];
            }
    }
    __syncthreads();
    if (tid < 64) {
        float s = 0.f;
#pragma unroll
        for (int w = 0; w < 8; ++w) s += scpart[w][tid];
        scores[(size_t)b * T + t0 + tid] = s;
    }
}

__global__ __launch_bounds__(256) void softmax_kernel(const float* __restrict__ sc,
                                                      float* __restrict__ out) {
    int b = blockIdx.x;
    int tid = threadIdx.x;
    int wave = tid >> 6, lane = tid & 63;
    const float* row = sc + (size_t)b * T;
    float vals[8];
    float m = -1e30f;
#pragma unroll
    for (int i = 0; i < 8; ++i) { vals[i] = row[tid + 256 * i]; m = fmaxf(m, vals[i]); }
#pragma unroll
    for (int s = 1; s < 64; s <<= 1) m = fmaxf(m, __shfl_xor(m, s));
    __shared__ float red[4];
    __shared__ float red2[4];
    if (lane == 0) red[wave] = m;
    __syncthreads();
    m = fmaxf(fmaxf(red[0], red[1]), fmaxf(red[2], red[3]));
    float sum = 0.f;
#pragma unroll
    for (int i = 0; i < 8; ++i) { vals[i] = expf(vals[i] - m); sum += vals[i]; }
#pragma unroll
    for (int s = 1; s < 64; s <<= 1) sum += __shfl_xor(sum, s);
    if (lane == 0) red2[wave] = sum;
    __syncthreads();
    sum = red2[0] + red2[1] + red2[2] + red2[3];
    float inv = 1.0f / sum;
#pragma unroll
    for (int i = 0; i < 8; ++i) out[(size_t)b * T + tid + 256 * i] = vals[i] * inv;
}

extern "C" void kernel_launch(void* const* d_in, const int* in_sizes, int n_in,
                              void* d_out, int out_size, void* d_ws, size_t ws_size,
                              hipStream_t stream) {
    (void)in_sizes; (void)n_in; (void)out_size; (void)ws_size;
    const float* hidden = (const float*)d_in[0];   // [1,B,H]
    const float* enc    = (const float*)d_in[1];   // [B,T,H]
    const float* W      = (const float*)d_in[2];   // [H,2H]
    const float* bias   = (const float*)d_in[3];   // [H]
    const float* v      = (const float*)d_in[4];   // [H]
    float* out = (float*)d_out;                    // [B,1,T]

    unsigned short* Wp = (unsigned short*)d_ws;                              // 2 MB
    float* hp = (float*)((char*)d_ws + 2 * 1024 * 1024);                     // 128 KB
    float* sc = (float*)((char*)d_ws + 2 * 1024 * 1024 + 128 * 1024);        // 256 KB

    prep_w_kernel<<<dim3(512), dim3(256), 0, stream>>>(W, Wp);
    prep_hp_kernel<<<dim3(8, B), dim3(128), 0, stream>>>(hidden, W, bias, hp);
    energy_kernel<<<dim3(T / 64, B), dim3(512), 0, stream>>>(enc, hp, v, Wp, sc);
    softmax_kernel<<<dim3(B), dim3(256), 0, stream>>>(sc, out);
}

// Round 3
// 244.180 us; speedup vs baseline: 1.2378x; 1.0101x over previous
//
#include <hip/hip_runtime.h>
#include <hip/hip_bf16.h>

#define H 1024
#define T 2048
#define B 32
#define BK 128
#define NCHUNK 8

typedef __attribute__((ext_vector_type(8))) __bf16 bf16x8;
typedef __attribute__((ext_vector_type(16))) float f32x16;
typedef __attribute__((ext_vector_type(8))) unsigned short u16x8;

__device__ __forceinline__ unsigned short f2bf(float f) {
    unsigned int x = __float_as_uint(f);
    x += 0x7fffu + ((x >> 16) & 1u);
    return (unsigned short)(x >> 16);
}

__device__ __forceinline__ float fast_tanh(float x) {
    float t = __expf(2.0f * x);
    return 1.0f - 2.0f * __builtin_amdgcn_rcpf(t + 1.0f);
}

// Pack W2 = W[:, H:2H] into bf16, layout Wp[kg][n][8] (kg = k>>3), 16B per (kg,n)
__global__ __launch_bounds__(256) void prep_w_kernel(const float* __restrict__ W,
                                                     unsigned short* __restrict__ Wp) {
    int gid = blockIdx.x * 256 + threadIdx.x;   // 131072 total
    int n = gid & (H - 1);
    int kg = gid >> 10;                          // 0..127
    const float* srcp = W + (size_t)n * (2 * H) + H + kg * 8;
    float4 f0 = *(const float4*)(srcp);
    float4 f1 = *(const float4*)(srcp + 4);
    u16x8 o;
    o[0] = f2bf(f0.x); o[1] = f2bf(f0.y); o[2] = f2bf(f0.z); o[3] = f2bf(f0.w);
    o[4] = f2bf(f1.x); o[5] = f2bf(f1.y); o[6] = f2bf(f1.z); o[7] = f2bf(f1.w);
    *(u16x8*)(Wp + (size_t)gid * 8) = o;
}

// hp[b][h] = sum_d hidden[b][d] * W[h][d] + bias[h]   (fp32, exact part)
__global__ __launch_bounds__(128) void prep_hp_kernel(const float* __restrict__ hidden,
                                                      const float* __restrict__ W,
                                                      const float* __restrict__ bias,
                                                      float* __restrict__ hp) {
    int b = blockIdx.y;
    int h = blockIdx.x * 128 + threadIdx.x;
    const float* hid = hidden + (size_t)b * H;
    const float* wr = W + (size_t)h * (2 * H);
    float acc = 0.f;
    for (int d = 0; d < H; d += 4) {
        float4 wv = *(const float4*)(wr + d);
        float4 hv = *(const float4*)(hid + d);
        acc += wv.x * hv.x + wv.y * hv.y + wv.z * hv.z + wv.w * hv.w;
    }
    hp[(size_t)b * H + h] = acc + bias[h];
}

// Fused energy+score kernel. 1024 threads = 16 waves; wave w owns cols [64w, 64w+64).
// LDS A-chunk: 16B unit at [kslot][row^kslot&7] -> byte kslot*1024 + ((row^(kslot&7))*16),
// kslot = k-group of 8 within the 128-k chunk (0..15), row 0..63.
__global__ __launch_bounds__(1024, 4) void energy_kernel(const float* __restrict__ enc,
                                                         const float* __restrict__ hp,
                                                         const float* __restrict__ vvec,
                                                         const unsigned short* __restrict__ Wp,
                                                         float* __restrict__ scores) {
    __shared__ __align__(16) unsigned short Abuf[2][NCHUNK * 1024];  // 2 x 16 KB
    __shared__ float scpart[16][64];

    const int tid = threadIdx.x;
    const int b = blockIdx.y;
    const int t0 = blockIdx.x * 64;
    const int wave = tid >> 6;
    const int lane = tid & 63;
    const int l31 = lane & 31;
    const int hi = lane >> 5;

    // staging: row = tid>>4 (0..63), kslot = tid&15 -> 8 consecutive k (32B global)
    const int st_row = tid >> 4;
    const int st_ks = tid & 15;
    const float* st_src = enc + ((size_t)b * T + t0 + st_row) * H + st_ks * 8;
    char* st_dst = (char*)&Abuf[0][0] + st_ks * 1024 + ((st_row ^ (st_ks & 7)) * 16);

    const char* Abase = (const char*)&Abuf[0][0];
    const int l31x = l31;  // row base for rg=0; rg=1 adds 512 bytes

    // B cols for this wave: n = wave*64 + cg*32 + l31; kg index folds hi
    const unsigned short* wp_col = Wp + (size_t)(wave * 64 + l31) * 8 + (size_t)hi * (H * 8);

    f32x16 acc[2][2];
#pragma unroll
    for (int rg = 0; rg < 2; ++rg)
#pragma unroll
        for (int cg = 0; cg < 2; ++cg)
#pragma unroll
            for (int i = 0; i < 16; ++i) acc[rg][cg][i] = 0.f;

    // ---- prologue: stage chunk 0 ----
    {
        float4 f0 = *(const float4*)(st_src + 0);
        float4 f1 = *(const float4*)(st_src + 4);
        u16x8 o;
        o[0] = f2bf(f0.x); o[1] = f2bf(f0.y); o[2] = f2bf(f0.z); o[3] = f2bf(f0.w);
        o[4] = f2bf(f1.x); o[5] = f2bf(f1.y); o[6] = f2bf(f1.z); o[7] = f2bf(f1.w);
        *(u16x8*)(st_dst) = o;
    }
    __syncthreads();

    for (int j = 0; j < NCHUNK; ++j) {
        float4 f0, f1;
        const bool pf = (j < NCHUNK - 1);
        if (pf) {
            const float* p = st_src + (j + 1) * BK;
            f0 = *(const float4*)(p + 0);
            f1 = *(const float4*)(p + 4);
        }
        const char* Ab = Abase + (j & 1) * 16384;
        const unsigned short* wpj = wp_col + (size_t)(j * 16) * (H * 8);
#pragma unroll
        for (int ki = 0; ki < 8; ++ki) {
            const int kslot = ki * 2 + hi;
            const char* ap = Ab + kslot * 1024 + ((l31x ^ (kslot & 7)) * 16);
            bf16x8 a0 = *(const bf16x8*)(ap);
            bf16x8 a1 = *(const bf16x8*)(ap + 512);
            const unsigned short* wpk = wpj + (size_t)(ki * 2) * (H * 8);
            bf16x8 b0 = *(const bf16x8*)(wpk + 0 * 256);
            bf16x8 b1 = *(const bf16x8*)(wpk + 1 * 256);
            acc[0][0] = __builtin_amdgcn_mfma_f32_32x32x16_bf16(a0, b0, acc[0][0], 0, 0, 0);
            acc[0][1] = __builtin_amdgcn_mfma_f32_32x32x16_bf16(a0, b1, acc[0][1], 0, 0, 0);
            acc[1][0] = __builtin_amdgcn_mfma_f32_32x32x16_bf16(a1, b0, acc[1][0], 0, 0, 0);
            acc[1][1] = __builtin_amdgcn_mfma_f32_32x32x16_bf16(a1, b1, acc[1][1], 0, 0, 0);
        }
        if (pf) {
            u16x8 o;
            o[0] = f2bf(f0.x); o[1] = f2bf(f0.y); o[2] = f2bf(f0.z); o[3] = f2bf(f0.w);
            o[4] = f2bf(f1.x); o[5] = f2bf(f1.y); o[6] = f2bf(f1.z); o[7] = f2bf(f1.w);
            *(u16x8*)(st_dst + ((j + 1) & 1) * 16384) = o;
        }
        __syncthreads();
    }

    // ---- fused epilogue: tanh + v-dot ----
    float pscore[2][16];
#pragma unroll
    for (int rg = 0; rg < 2; ++rg)
#pragma unroll
        for (int r = 0; r < 16; ++r) pscore[rg][r] = 0.f;

    const size_t bH = (size_t)b * H;
#pragma unroll
    for (int cg = 0; cg < 2; ++cg) {
        const int col = wave * 64 + cg * 32 + l31;
        const float hpv = hp[bH + col];
        const float vv = vvec[col];
#pragma unroll
        for (int rg = 0; rg < 2; ++rg)
#pragma unroll
            for (int r = 0; r < 16; ++r)
                pscore[rg][r] += vv * fast_tanh(acc[rg][cg][r] + hpv);
    }

#pragma unroll
    for (int rg = 0; rg < 2; ++rg)
#pragma unroll
        for (int r = 0; r < 16; ++r) {
            float s = pscore[rg][r];
            s += __shfl_xor(s, 1);
            s += __shfl_xor(s, 2);
            s += __shfl_xor(s, 4);
            s += __shfl_xor(s, 8);
            s += __shfl_xor(s, 16);
            pscore[rg][r] = s;
        }
    if (l31 == 0) {
#pragma unroll
        for (int rg = 0; rg < 2; ++rg)
#pragma unroll
            for (int r = 0; r < 16; ++r) {
                int m = (r & 3) + 8 * (r >> 2) + 4 * hi + rg * 32;
                scpart[wave][m] = pscore[rg][r];
            }
    }
    __syncthreads();
    if (tid < 64) {
        float s = 0.f;
#pragma unroll
        for (int w = 0; w < 16; ++w) s += scpart[w][tid];
        scores[(size_t)b * T + t0 + tid] = s;
    }
}

__global__ __launch_bounds__(256) void softmax_kernel(const float* __restrict__ sc,
                                                      float* __restrict__ out) {
    int b = blockIdx.x;
    int tid = threadIdx.x;
    int wave = tid >> 6, lane = tid & 63;
    const float* row = sc + (size_t)b * T;
    float vals[8];
    float m = -1e30f;
#pragma unroll
    for (int i = 0; i < 8; ++i) { vals[i] = row[tid + 256 * i]; m = fmaxf(m, vals[i]); }
#pragma unroll
    for (int s = 1; s < 64; s <<= 1) m = fmaxf(m, __shfl_xor(m, s));
    __shared__ float red[4];
    __shared__ float red2[4];
    if (lane == 0) red[wave] = m;
    __syncthreads();
    m = fmaxf(fmaxf(red[0], red[1]), fmaxf(red[2], red[3]));
    float sum = 0.f;
#pragma unroll
    for (int i = 0; i < 8; ++i) { vals[i] = expf(vals[i] - m); sum += vals[i]; }
#pragma unroll
    for (int s = 1; s < 64; s <<= 1) sum += __shfl_xor(sum, s);
    if (lane == 0) red2[wave] = sum;
    __syncthreads();
    sum = red2[0] + red2[1] + red2[2] + red2[3];
    float inv = 1.0f / sum;
#pragma unroll
    for (int i = 0; i < 8; ++i) out[(size_t)b * T + tid + 256 * i] = vals[i] * inv;
}

extern "C" void kernel_launch(void* const* d_in, const int* in_sizes, int n_in,
                              void* d_out, int out_size, void* d_ws, size_t ws_size,
                              hipStream_t stream) {
    (void)in_sizes; (void)n_in; (void)out_size; (void)ws_size;
    const float* hidden = (const float*)d_in[0];   // [1,B,H]
    const float* enc    = (const float*)d_in[1];   // [B,T,H]
    const float* W      = (const float*)d_in[2];   // [H,2H]
    const float* bias   = (const float*)d_in[3];   // [H]
    const float* v      = (const float*)d_in[4];   // [H]
    float* out = (float*)d_out;                    // [B,1,T]

    unsigned short* Wp = (unsigned short*)d_ws;                              // 2 MB
    float* hp = (float*)((char*)d_ws + 2 * 1024 * 1024);                     // 128 KB
    float* sc = (float*)((char*)d_ws + 2 * 1024 * 1024 + 128 * 1024);        // 256 KB

    prep_w_kernel<<<dim3(512), dim3(256), 0, stream>>>(W, Wp);
    prep_hp_kernel<<<dim3(8, B), dim3(128), 0, stream>>>(hidden, W, bias, hp);
    energy_kernel<<<dim3(T / 64, B), dim3(1024), 0, stream>>>(enc, hp, v, Wp, sc);
    softmax_kernel<<<dim3(B), dim3(256), 0, stream>>>(sc, out);
}

// Round 4
// 235.895 us; speedup vs baseline: 1.2813x; 1.0351x over previous
//
#include <hip/hip_runtime.h>
#include <hip/hip_bf16.h>

#define H 1024
#define T 2048
#define B 32
#define BM 128        // rows per block
#define BKC 64        // k per LDS chunk
#define NCHUNK 16     // H / BKC
#define NCOLT 2       // column tiles
#define BCOLS 512     // cols per block

typedef __attribute__((ext_vector_type(8))) __bf16 bf16x8;
typedef __attribute__((ext_vector_type(16))) float f32x16;
typedef __attribute__((ext_vector_type(8))) unsigned short u16x8;

__device__ __forceinline__ unsigned short f2bf(float f) {
    unsigned int x = __float_as_uint(f);
    x += 0x7fffu + ((x >> 16) & 1u);
    return (unsigned short)(x >> 16);
}

__device__ __forceinline__ float fast_tanh(float x) {
    float t = __expf(2.0f * x);
    return 1.0f - 2.0f * __builtin_amdgcn_rcpf(t + 1.0f);
}

// row -> swizzled byte offset inside one kslot page (bank-spreads rows 8 apart)
__device__ __forceinline__ int rswz(int r) {
    return (r << 4) ^ ((r & 0x38) << 1);
}

// Pack W2 = W[:, H:2H] into bf16, layout Wp[kg][n][8] (kg = k>>3), 16B per (kg,n)
__global__ __launch_bounds__(256) void prep_w_kernel(const float* __restrict__ W,
                                                     unsigned short* __restrict__ Wp) {
    int gid = blockIdx.x * 256 + threadIdx.x;   // 131072 total
    int n = gid & (H - 1);
    int kg = gid >> 10;                          // 0..127
    const float* srcp = W + (size_t)n * (2 * H) + H + kg * 8;
    float4 f0 = *(const float4*)(srcp);
    float4 f1 = *(const float4*)(srcp + 4);
    u16x8 o;
    o[0] = f2bf(f0.x); o[1] = f2bf(f0.y); o[2] = f2bf(f0.z); o[3] = f2bf(f0.w);
    o[4] = f2bf(f1.x); o[5] = f2bf(f1.y); o[6] = f2bf(f1.z); o[7] = f2bf(f1.w);
    *(u16x8*)(Wp + (size_t)gid * 8) = o;
}

// hp[b][h] = sum_d hidden[b][d] * W[h][d] + bias[h]   (fp32, exact part)
__global__ __launch_bounds__(128) void prep_hp_kernel(const float* __restrict__ hidden,
                                                      const float* __restrict__ W,
                                                      const float* __restrict__ bias,
                                                      float* __restrict__ hp) {
    int b = blockIdx.y;
    int h = blockIdx.x * 128 + threadIdx.x;
    const float* hid = hidden + (size_t)b * H;
    const float* wr = W + (size_t)h * (2 * H);
    float acc = 0.f;
    for (int d = 0; d < H; d += 4) {
        float4 wv = *(const float4*)(wr + d);
        float4 hv = *(const float4*)(hid + d);
        acc += wv.x * hv.x + wv.y * hv.y + wv.z * hv.z + wv.w * hv.w;
    }
    hp[(size_t)b * H + h] = acc + bias[h];
}

#define MFMA32(A, Bv, C) __builtin_amdgcn_mfma_f32_32x32x16_bf16(A, Bv, C, 0, 0, 0)

// Block = (t-tile of 128 rows, col-tile of 512, b). 8 waves; wave owns 64 cols x all 128 rows.
// LDS A-chunk: 16B unit at kslot*2048 + rswz(row); kslot = k-group of 8 within 64-k chunk.
__global__ __launch_bounds__(512, 2) void energy_kernel(const float* __restrict__ enc,
                                                        const float* __restrict__ hp,
                                                        const float* __restrict__ vvec,
                                                        const unsigned short* __restrict__ Wp,
                                                        float* __restrict__ sc_part) {
    __shared__ __align__(16) unsigned short Abuf[2][BM * BKC];  // 2 x 16 KB
    __shared__ float scpart[8][BM];

    const int tid = threadIdx.x;
    const int b = blockIdx.z;
    const int t0 = blockIdx.x * BM;
    const int c0 = blockIdx.y * BCOLS;
    const int wave = tid >> 6;
    const int lane = tid & 63;
    const int l31 = lane & 31;
    const int hi = lane >> 5;

    // staging: thread -> kslot = tid&7 (8 consecutive k), rows 2*(tid>>3), +1
    const int st_ks = tid & 7;
    const int st_rb = tid >> 3;                 // 0..63
    const int r0 = st_rb * 2, r1 = r0 + 1;
    const float* st_src0 = enc + ((size_t)b * T + t0 + r0) * H + st_ks * 8;
    const float* st_src1 = st_src0 + H;
    char* Ab0 = (char*)&Abuf[0][0];
    char* st_d0 = Ab0 + st_ks * 2048 + rswz(r0);
    char* st_d1 = Ab0 + st_ks * 2048 + rswz(r1);

    // a-frag swizzled offsets for this lane's 4 row-groups
    const int a_off0 = rswz(0 * 32 + l31);
    const int a_off1 = rswz(1 * 32 + l31);
    const int a_off2 = rswz(2 * 32 + l31);
    const int a_off3 = rswz(3 * 32 + l31);

    // B stream: per flat-iteration it (0..63), kg = it*2 + hi
    const unsigned short* wp_base = Wp + (size_t)(c0 + wave * 64 + l31) * 8 + (size_t)hi * (H * 8);

    f32x16 acc[4][2];
#pragma unroll
    for (int rg = 0; rg < 4; ++rg)
#pragma unroll
        for (int cg = 0; cg < 2; ++cg)
#pragma unroll
            for (int i = 0; i < 16; ++i) acc[rg][cg][i] = 0.f;

    // ---- prologue: stage chunk 0, load B it=0 ----
    {
        float4 f0 = *(const float4*)(st_src0);
        float4 f1 = *(const float4*)(st_src0 + 4);
        float4 f2 = *(const float4*)(st_src1);
        float4 f3 = *(const float4*)(st_src1 + 4);
        u16x8 o0, o1;
        o0[0] = f2bf(f0.x); o0[1] = f2bf(f0.y); o0[2] = f2bf(f0.z); o0[3] = f2bf(f0.w);
        o0[4] = f2bf(f1.x); o0[5] = f2bf(f1.y); o0[6] = f2bf(f1.z); o0[7] = f2bf(f1.w);
        o1[0] = f2bf(f2.x); o1[1] = f2bf(f2.y); o1[2] = f2bf(f2.z); o1[3] = f2bf(f2.w);
        o1[4] = f2bf(f3.x); o1[5] = f2bf(f3.y); o1[6] = f2bf(f3.z); o1[7] = f2bf(f3.w);
        *(u16x8*)st_d0 = o0;
        *(u16x8*)st_d1 = o1;
    }
    bf16x8 bpe0 = *(const bf16x8*)(wp_base);          // it=0 (even slot)
    bf16x8 bpe1 = *(const bf16x8*)(wp_base + 256);
    bf16x8 bpo0, bpo1;                                 // odd slot
    __syncthreads();

#define KI_STEP(KI, CUR0, CUR1, NXT0, NXT1)                                   \
    {                                                                          \
        const int it = j * 4 + (KI);                                           \
        if (it < 63) {                                                         \
            const unsigned short* bp = wp_base + (size_t)(it + 1) * (H * 16);  \
            NXT0 = *(const bf16x8*)(bp);                                       \
            NXT1 = *(const bf16x8*)(bp + 256);                                 \
        }                                                                      \
        const char* ap = Ab + (((KI) * 2 + hi) * 2048);                        \
        bf16x8 a0 = *(const bf16x8*)(ap + a_off0);                             \
        bf16x8 a1 = *(const bf16x8*)(ap + a_off1);                             \
        bf16x8 a2 = *(const bf16x8*)(ap + a_off2);                             \
        bf16x8 a3 = *(const bf16x8*)(ap + a_off3);                             \
        acc[0][0] = MFMA32(a0, CUR0, acc[0][0]);                               \
        acc[0][1] = MFMA32(a0, CUR1, acc[0][1]);                               \
        acc[1][0] = MFMA32(a1, CUR0, acc[1][0]);                               \
        acc[1][1] = MFMA32(a1, CUR1, acc[1][1]);                               \
        acc[2][0] = MFMA32(a2, CUR0, acc[2][0]);                               \
        acc[2][1] = MFMA32(a2, CUR1, acc[2][1]);                               \
        acc[3][0] = MFMA32(a3, CUR0, acc[3][0]);                               \
        acc[3][1] = MFMA32(a3, CUR1, acc[3][1]);                               \
    }

    for (int j = 0; j < NCHUNK; ++j) {
        // issue A prefetch for chunk j+1
        float4 f0, f1, f2, f3;
        const bool pf = (j < NCHUNK - 1);
        if (pf) {
            const float* p0 = st_src0 + (j + 1) * BKC;
            const float* p1 = st_src1 + (j + 1) * BKC;
            f0 = *(const float4*)(p0);
            f1 = *(const float4*)(p0 + 4);
            f2 = *(const float4*)(p1);
            f3 = *(const float4*)(p1 + 4);
        }
        const char* Ab = Ab0 + (j & 1) * 16384;
        KI_STEP(0, bpe0, bpe1, bpo0, bpo1)
        KI_STEP(1, bpo0, bpo1, bpe0, bpe1)
        KI_STEP(2, bpe0, bpe1, bpo0, bpo1)
        KI_STEP(3, bpo0, bpo1, bpe0, bpe1)
        if (pf) {
            u16x8 o0, o1;
            o0[0] = f2bf(f0.x); o0[1] = f2bf(f0.y); o0[2] = f2bf(f0.z); o0[3] = f2bf(f0.w);
            o0[4] = f2bf(f1.x); o0[5] = f2bf(f1.y); o0[6] = f2bf(f1.z); o0[7] = f2bf(f1.w);
            o1[0] = f2bf(f2.x); o1[1] = f2bf(f2.y); o1[2] = f2bf(f2.z); o1[3] = f2bf(f2.w);
            o1[4] = f2bf(f3.x); o1[5] = f2bf(f3.y); o1[6] = f2bf(f3.z); o1[7] = f2bf(f3.w);
            char* d0 = st_d0 + ((j + 1) & 1) * 16384;
            char* d1 = st_d1 + ((j + 1) & 1) * 16384;
            *(u16x8*)d0 = o0;
            *(u16x8*)d1 = o1;
        }
        __syncthreads();
    }
#undef KI_STEP

    // ---- fused epilogue: tanh + v-dot over this block's 512 cols ----
    float psc[4][16];
#pragma unroll
    for (int rg = 0; rg < 4; ++rg)
#pragma unroll
        for (int r = 0; r < 16; ++r) psc[rg][r] = 0.f;

    const size_t bH = (size_t)b * H;
#pragma unroll
    for (int cg = 0; cg < 2; ++cg) {
        const int col = c0 + wave * 64 + cg * 32 + l31;
        const float hpv = hp[bH + col];
        const float vv = vvec[col];
#pragma unroll
        for (int rg = 0; rg < 4; ++rg)
#pragma unroll
            for (int r = 0; r < 16; ++r)
                psc[rg][r] += vv * fast_tanh(acc[rg][cg][r] + hpv);
    }

#pragma unroll
    for (int rg = 0; rg < 4; ++rg)
#pragma unroll
        for (int r = 0; r < 16; ++r) {
            float s = psc[rg][r];
            s += __shfl_xor(s, 1);
            s += __shfl_xor(s, 2);
            s += __shfl_xor(s, 4);
            s += __shfl_xor(s, 8);
            s += __shfl_xor(s, 16);
            psc[rg][r] = s;
        }
    if (l31 == 0) {
#pragma unroll
        for (int rg = 0; rg < 4; ++rg)
#pragma unroll
            for (int r = 0; r < 16; ++r) {
                int m = rg * 32 + (r & 3) + 8 * (r >> 2) + 4 * hi;
                scpart[wave][m] = psc[rg][r];
            }
    }
    __syncthreads();
    if (tid < BM) {
        float s = 0.f;
#pragma unroll
        for (int w = 0; w < 8; ++w) s += scpart[w][tid];
        sc_part[((size_t)blockIdx.y * B + b) * T + t0 + tid] = s;
    }
}

__global__ __launch_bounds__(256) void softmax_kernel(const float* __restrict__ sc,
                                                      float* __restrict__ out) {
    int b = blockIdx.x;
    int tid = threadIdx.x;
    int wave = tid >> 6, lane = tid & 63;
    const float* row0 = sc + (size_t)b * T;
    const float* row1 = sc + ((size_t)B + b) * T;
    float vals[8];
    float m = -1e30f;
#pragma unroll
    for (int i = 0; i < 8; ++i) {
        int idx = tid + 256 * i;
        vals[i] = row0[idx] + row1[idx];
        m = fmaxf(m, vals[i]);
    }
#pragma unroll
    for (int s = 1; s < 64; s <<= 1) m = fmaxf(m, __shfl_xor(m, s));
    __shared__ float red[4];
    __shared__ float red2[4];
    if (lane == 0) red[wave] = m;
    __syncthreads();
    m = fmaxf(fmaxf(red[0], red[1]), fmaxf(red[2], red[3]));
    float sum = 0.f;
#pragma unroll
    for (int i = 0; i < 8; ++i) { vals[i] = expf(vals[i] - m); sum += vals[i]; }
#pragma unroll
    for (int s = 1; s < 64; s <<= 1) sum += __shfl_xor(sum, s);
    if (lane == 0) red2[wave] = sum;
    __syncthreads();
    sum = red2[0] + red2[1] + red2[2] + red2[3];
    float inv = 1.0f / sum;
#pragma unroll
    for (int i = 0; i < 8; ++i) out[(size_t)b * T + tid + 256 * i] = vals[i] * inv;
}

extern "C" void kernel_launch(void* const* d_in, const int* in_sizes, int n_in,
                              void* d_out, int out_size, void* d_ws, size_t ws_size,
                              hipStream_t stream) {
    (void)in_sizes; (void)n_in; (void)out_size; (void)ws_size;
    const float* hidden = (const float*)d_in[0];   // [1,B,H]
    const float* enc    = (const float*)d_in[1];   // [B,T,H]
    const float* W      = (const float*)d_in[2];   // [H,2H]
    const float* bias   = (const float*)d_in[3];   // [H]
    const float* v      = (const float*)d_in[4];   // [H]
    float* out = (float*)d_out;                    // [B,1,T]

    unsigned short* Wp = (unsigned short*)d_ws;                              // 2 MB
    float* hp = (float*)((char*)d_ws + 2 * 1024 * 1024);                     // 128 KB
    float* sc = (float*)((char*)d_ws + 2 * 1024 * 1024 + 128 * 1024);        // 512 KB (2 partials)

    prep_w_kernel<<<dim3(512), dim3(256), 0, stream>>>(W, Wp);
    prep_hp_kernel<<<dim3(8, B), dim3(128), 0, stream>>>(hidden, W, bias, hp);
    energy_kernel<<<dim3(T / BM, NCOLT, B), dim3(512), 0, stream>>>(enc, hp, v, Wp, sc);
    softmax_kernel<<<dim3(B), dim3(256), 0, stream>>>(sc, out);
}